// Round 7
// baseline (127.128 us; speedup 1.0000x reference)
//
#include <hip/hip_runtime.h>
#include <math.h>

#define EPSF 1e-10f
#define TILE 32      // k_main rows per tile
#define TILEH 64     // k_hist rows per tile

struct WS {
  double sum_mse, sum_ce;
  float mn[10], mx[10];
};

typedef __attribute__((address_space(3))) unsigned int lds_u32_t;
typedef __attribute__((address_space(1))) const unsigned int glb_u32_t;
__device__ __forceinline__ void load_lds16(const void* g, void* l){
  __builtin_amdgcn_global_load_lds((glb_u32_t*)g, (lds_u32_t*)l, 16, 0, 0);
}

// CE over one softmax block, operands in LDS (compile-time offsets -> registers).
template<int S, int E>
__device__ __forceinline__ float ce_block_lds(const float* __restrict__ d,
                                              const float* __restrict__ t){
  constexpr int N = E - S;
  float dv[N];
  #pragma unroll
  for (int j = 0; j < N; j++) dv[j] = d[S + j];
  float mx = dv[0];
  #pragma unroll
  for (int j = 1; j < N; j++) mx = fmaxf(mx, dv[j]);
  float se = 0.f, dot = 0.f;
  #pragma unroll
  for (int j = 0; j < N; j++){ se += __expf(dv[j] - mx); dot += t[S + j] * dv[j]; }
  return mx + __logf(se) - dot;
}

__global__ void k_main(const float* __restrict__ enc, const float* __restrict__ dec,
                       const float* __restrict__ tru,
                       double* __restrict__ pmMse, double* __restrict__ pmCe,
                       float* __restrict__ pmMn, float* __restrict__ pmMx,
                       int B, int nbm){
  __shared__ alignas(16) float bufD[TILE * 50];
  __shared__ alignas(16) float bufT[TILE * 50];
  __shared__ alignas(16) float bufE[TILE * 10];
  __shared__ double sMse[4], sCe[4];
  __shared__ float  sMn[4][10], sMx[4][10];

  const int tid  = threadIdx.x;
  const int wave = tid >> 6;
  const int lane = tid & 63;
  const int h    = tid >> 5;   // half-wave column group 0..7
  const int row  = tid & 31;

  float mn[10], mx[10];
  #pragma unroll
  for (int c = 0; c < 10; c++){ mn[c] = 3.4e38f; mx[c] = -3.4e38f; }
  float mse_acc = 0.f, ce_acc = 0.f;

  const int nTiles = (B + TILE - 1) / TILE;

  auto stage = [&](int tl){
    const int rowsHere = min(TILE, B - tl * TILE);
    const size_t base50 = (size_t)tl * TILE * 50;
    const size_t base10 = (size_t)tl * TILE * 10;
    if (rowsHere == TILE){
      const float4* dp4 = reinterpret_cast<const float4*>(dec + base50);
      const float4* tp4 = reinterpret_cast<const float4*>(tru + base50);
      const float4* ep4 = reinterpret_cast<const float4*>(enc + base10);
      float4* bD = reinterpret_cast<float4*>(bufD);
      float4* bT = reinterpret_cast<float4*>(bufT);
      float4* bE = reinterpret_cast<float4*>(bufE);
      #pragma unroll
      for (int k = 0; k < 2; k++){        // 400 float4
        int i = tid + k * 256;
        if (i < 400){ load_lds16(dp4 + i, bD + i); }
      }
      #pragma unroll
      for (int k = 0; k < 2; k++){
        int i = tid + k * 256;
        if (i < 400){ load_lds16(tp4 + i, bT + i); }
      }
      { int i = tid; if (i < 80){ load_lds16(ep4 + i, bE + i); } }
    } else {
      const int nf = rowsHere * 50, ne = rowsHere * 10;
      for (int i = tid; i < nf; i += 256){ bufD[i] = dec[base50 + i]; bufT[i] = tru[base50 + i]; }
      for (int i = tid; i < ne; i += 256){ bufE[i] = enc[base10 + i]; }
    }
  };

  for (int tl = blockIdx.x; tl < nTiles; tl += nbm){
    stage(tl);
    __syncthreads();               // drains vmcnt + barrier

    const int rowsHere = min(TILE, B - tl * TILE);
    if (row < rowsHere){
      const float* d = bufD + row * 50;
      const float* t = bufT + row * 50;
      const float* e = bufE + row * 10;
      switch (h){
        case 0: {
          float m = 0.f;
          #pragma unroll
          for (int j = 0; j < 7; j++){ float df = d[j] - t[j]; m += df * df; }
          mse_acc += m;
          { float v = e[0]; mn[0] = fminf(mn[0], v); mx[0] = fmaxf(mx[0], v); }
          { float v = e[1]; mn[1] = fminf(mn[1], v); mx[1] = fmaxf(mx[1], v); }
        } break;
        case 1: {
          ce_acc += ce_block_lds< 7,19>(d, t);
          { float v = e[2]; mn[2] = fminf(mn[2], v); mx[2] = fmaxf(mx[2], v); }
        } break;
        case 2: {
          ce_acc += ce_block_lds<19,21>(d, t);
          ce_acc += ce_block_lds<21,25>(d, t);
          { float v = e[3]; mn[3] = fminf(mn[3], v); mx[3] = fmaxf(mx[3], v); }
        } break;
        case 3: {
          ce_acc += ce_block_lds<25,27>(d, t);
          ce_acc += ce_block_lds<27,29>(d, t);
          { float v = e[4]; mn[4] = fminf(mn[4], v); mx[4] = fmaxf(mx[4], v); }
        } break;
        case 4: {
          ce_acc += ce_block_lds<29,31>(d, t);
          ce_acc += ce_block_lds<31,34>(d, t);
          { float v = e[5]; mn[5] = fminf(mn[5], v); mx[5] = fmaxf(mx[5], v); }
          { float v = e[6]; mn[6] = fminf(mn[6], v); mx[6] = fmaxf(mx[6], v); }
        } break;
        case 5: {
          ce_acc += ce_block_lds<34,38>(d, t);
          { float v = e[7]; mn[7] = fminf(mn[7], v); mx[7] = fmaxf(mx[7], v); }
        } break;
        case 6: {
          ce_acc += ce_block_lds<38,50>(d, t);
          { float v = e[8]; mn[8] = fminf(mn[8], v); mx[8] = fmaxf(mx[8], v); }
        } break;
        default: {
          { float v = e[9]; mn[9] = fminf(mn[9], v); mx[9] = fmaxf(mx[9], v); }
        } break;
      }
    }
    __syncthreads();               // protect LDS before next stage
  }

  // ---- wave-level reduction ----
  #pragma unroll
  for (int c = 0; c < 10; c++){
    #pragma unroll
    for (int o = 32; o >= 1; o >>= 1){
      mn[c] = fminf(mn[c], __shfl_xor(mn[c], o));
      mx[c] = fmaxf(mx[c], __shfl_xor(mx[c], o));
    }
  }
  double mseD = (double)mse_acc, ceD = (double)ce_acc;
  #pragma unroll
  for (int o = 32; o >= 1; o >>= 1){
    mseD += __shfl_xor(mseD, o);
    ceD  += __shfl_xor(ceD,  o);
  }
  if (lane == 0){
    sMse[wave] = mseD; sCe[wave] = ceD;
    #pragma unroll
    for (int c = 0; c < 10; c++){ sMn[wave][c] = mn[c]; sMx[wave][c] = mx[c]; }
  }
  __syncthreads();
  if (tid == 0){
    pmMse[blockIdx.x] = sMse[0] + sMse[1] + sMse[2] + sMse[3];
    pmCe[blockIdx.x]  = sCe[0]  + sCe[1]  + sCe[2]  + sCe[3];
    #pragma unroll
    for (int c = 0; c < 10; c++){
      pmMn[c * nbm + blockIdx.x] = fminf(fminf(sMn[0][c], sMn[1][c]), fminf(sMn[2][c], sMn[3][c]));
      pmMx[c * nbm + blockIdx.x] = fmaxf(fmaxf(sMx[0][c], sMx[1][c]), fmaxf(sMx[2][c], sMx[3][c]));
    }
  }
}

// 1024 threads, SoA coalesced, high MLP (22 independent streams)
__global__ void k_reduce(const double* __restrict__ pmMse, const double* __restrict__ pmCe,
                         const float* __restrict__ pmMn, const float* __restrict__ pmMx,
                         WS* __restrict__ ws, int nbm){
  __shared__ double sM[16], sC[16];
  __shared__ float  sMn[16][10], sMx[16][10];
  const int tid  = threadIdx.x;   // 1024
  const int wave = tid >> 6;
  const int lane = tid & 63;

  double ms = 0.0, ce = 0.0;
  float mn[10], mx[10];
  #pragma unroll
  for (int c = 0; c < 10; c++){ mn[c] = 3.4e38f; mx[c] = -3.4e38f; }
  for (int i = tid; i < nbm; i += 1024){
    ms += pmMse[i]; ce += pmCe[i];
    #pragma unroll
    for (int c = 0; c < 10; c++){
      mn[c] = fminf(mn[c], pmMn[c * nbm + i]);
      mx[c] = fmaxf(mx[c], pmMx[c * nbm + i]);
    }
  }
  #pragma unroll
  for (int o = 32; o >= 1; o >>= 1){
    ms += __shfl_xor(ms, o);
    ce += __shfl_xor(ce, o);
    #pragma unroll
    for (int c = 0; c < 10; c++){
      mn[c] = fminf(mn[c], __shfl_xor(mn[c], o));
      mx[c] = fmaxf(mx[c], __shfl_xor(mx[c], o));
    }
  }
  if (lane == 0){
    sM[wave] = ms; sC[wave] = ce;
    #pragma unroll
    for (int c = 0; c < 10; c++){ sMn[wave][c] = mn[c]; sMx[wave][c] = mx[c]; }
  }
  __syncthreads();
  if (tid == 0){
    double tm = 0.0, tc = 0.0;
    float rmn[10], rmx[10];
    #pragma unroll
    for (int c = 0; c < 10; c++){ rmn[c] = 3.4e38f; rmx[c] = -3.4e38f; }
    #pragma unroll
    for (int w = 0; w < 16; w++){
      tm += sM[w]; tc += sC[w];
      #pragma unroll
      for (int c = 0; c < 10; c++){
        rmn[c] = fminf(rmn[c], sMn[w][c]);
        rmx[c] = fmaxf(rmx[c], sMx[w][c]);
      }
    }
    ws->sum_mse = tm; ws->sum_ce = tc;
    #pragma unroll
    for (int c = 0; c < 10; c++){ ws->mn[c] = rmn[c]; ws->mx[c] = rmx[c]; }
  }
}

__global__ void k_hist(const float* __restrict__ enc, const float* __restrict__ lab,
                       const WS* __restrict__ ws, unsigned* __restrict__ ph,
                       int B, int nbh){
  __shared__ unsigned int sh[202];
  __shared__ alignas(16) float bufE[2][TILEH * 10];
  __shared__ alignas(16) float bufL[2][TILEH * 3];

  const int tid  = threadIdx.x;
  const int wave = tid >> 6;
  const int lane = tid & 63;

  for (int i = tid; i < 202; i += 256) sh[i] = 0u;

  float mnv[10], wv[10];
  #pragma unroll
  for (int c = 0; c < 10; c++){
    float lo = ws->mn[c];
    float hi = ws->mx[c];
    mnv[c] = lo;
    wv[c]  = fmaxf(hi - lo, EPSF);
  }

  const int nTiles = (B + TILEH - 1) / TILEH;

  auto stage = [&](int b, int tl){
    const int rowsHere = min(TILEH, B - tl * TILEH);
    const size_t base10 = (size_t)tl * TILEH * 10;
    const size_t base3  = (size_t)tl * TILEH * 3;
    if (rowsHere == TILEH){
      const float4* ep4 = reinterpret_cast<const float4*>(enc + base10);
      const float4* lp4 = reinterpret_cast<const float4*>(lab + base3);
      float4* bE = reinterpret_cast<float4*>(bufE[b]);
      float4* bL = reinterpret_cast<float4*>(bufL[b]);
      { int i = tid; if (i < 160) load_lds16(ep4 + i, bE + i); }
      { int i = tid; if (i < 48)  load_lds16(lp4 + i, bL + i); }
    } else {
      const int ne = rowsHere * 10, nl = rowsHere * 3;
      for (int i = tid; i < ne; i += 256) bufE[b][i] = enc[base10 + i];
      for (int i = tid; i < nl; i += 256) bufL[b][i] = lab[base3 + i];
    }
  };

  const int t0 = blockIdx.x;
  if (t0 < nTiles) stage(0, t0);
  __syncthreads();

  int cur = 0;
  for (int tl = t0; tl < nTiles; tl += nbh){
    int nxt = tl + nbh;
    if (nxt < nTiles) stage(cur ^ 1, nxt);

    const int rowsHere = min(TILEH, B - tl * TILEH);
    const int rrow = lane;
    if (rrow < rowsHere){
      float g = bufL[cur][rrow * 3 + 1];
      int gi = (g == 0.0f) ? 0 : ((g == 1.0f) ? 1 : -1);
      if (gi >= 0){
        const float* e = bufE[cur] + rrow * 10;
        if (wave == 1) atomicAdd(&sh[200 + gi], 1u);
        #define DO_BIN(c) { \
          float bf = floorf((e[(c)] - mnv[(c)]) / wv[(c)] * 10.0f); \
          int b2 = (int)bf; b2 = b2 < 0 ? 0 : (b2 > 9 ? 9 : b2); \
          atomicAdd(&sh[gi * 100 + (c) * 10 + b2], 1u); }
        if (wave == 0){ DO_BIN(0) DO_BIN(1) DO_BIN(2) }
        else if (wave == 1){ DO_BIN(3) DO_BIN(4) }
        else if (wave == 2){ DO_BIN(5) DO_BIN(6) }
        else { DO_BIN(7) DO_BIN(8) DO_BIN(9) }
        #undef DO_BIN
      }
    }
    __syncthreads();
    cur ^= 1;
  }

  // transposed store: ph[entry * nbh + block]
  for (int i = tid; i < 202; i += 256) ph[(size_t)i * nbh + blockIdx.x] = sh[i];
}

// one block per histogram entry: coalesced sum over nbh partials, 4-way MLP
__global__ void k_hreduce(const unsigned* __restrict__ ph, float* __restrict__ histF, int nbh){
  __shared__ unsigned swv[4];
  const int e    = blockIdx.x;     // 0..201
  const int tid  = threadIdx.x;    // 256
  const int wave = tid >> 6;
  const int lane = tid & 63;
  const unsigned* p = ph + (size_t)e * nbh;
  unsigned s0 = 0, s1 = 0, s2 = 0, s3 = 0;
  int k = tid;
  for (; k + 768 < nbh; k += 1024){
    s0 += p[k]; s1 += p[k + 256]; s2 += p[k + 512]; s3 += p[k + 768];
  }
  for (; k < nbh; k += 256) s0 += p[k];
  unsigned s = s0 + s1 + s2 + s3;
  #pragma unroll
  for (int o = 32; o >= 1; o >>= 1) s += __shfl_xor(s, o);
  if (lane == 0) swv[wave] = s;
  __syncthreads();
  if (tid == 0) histF[e] = (float)(swv[0] + swv[1] + swv[2] + swv[3]);
}

__global__ void k_final(const float* __restrict__ histF, const WS* __restrict__ ws,
                        float* __restrict__ out, int B){
  const int tid = threadIdx.x;  // 64
  float dens = fmaxf(histF[200], 1.0f);
  float denm = fmaxf(histF[201], 1.0f);
  float kl = 0.f;
  for (int i = tid; i < 100; i += 64){
    float p = histF[i]       / dens;
    float q = histF[100 + i] / denm;
    if (p > 0.f) kl += p * logf(p / fmaxf(q, EPSF));
  }
  #pragma unroll
  for (int o = 32; o >= 1; o >>= 1) kl += __shfl_xor(kl, o);
  if (tid == 0){
    float mse = (float)(ws->sum_mse / (double)B);
    float ce  = (float)(ws->sum_ce  / (double)B);
    float akld = 0.5f * kl;
    out[0] = 0.5f * (mse + ce) + akld;
    out[1] = mse;
    out[2] = ce;
    out[3] = akld;
  }
}

extern "C" void kernel_launch(void* const* d_in, const int* in_sizes, int n_in,
                              void* d_out, int out_size, void* d_ws, size_t ws_size,
                              hipStream_t stream){
  const float* enc = (const float*)d_in[0];
  const float* dec = (const float*)d_in[1];
  const float* tru = (const float*)d_in[2];
  const float* lab = (const float*)d_in[3];
  int B = in_sizes[1] / 50;

  // workspace: [WS 128][pmMse 8*nbm][pmCe 8*nbm][pmMn 40*nbm][pmMx 40*nbm][ph 202*nbh*4][histF 1024]
  int nbm = 2048, nbh = 2048;
  while ((size_t)(128 + (size_t)nbm * 96 + (size_t)202 * nbh * 4 + 1024) > ws_size && nbm > 64){
    nbm >>= 1; nbh >>= 1;
  }
  char* w = (char*)d_ws;
  WS* ws = (WS*)w;
  double* pmMse = (double*)(w + 128);
  double* pmCe  = (double*)(w + 128 + (size_t)nbm * 8);
  float*  pmMn  = (float*)(w + 128 + (size_t)nbm * 16);
  float*  pmMx  = (float*)(w + 128 + (size_t)nbm * 16 + (size_t)nbm * 40);
  unsigned* ph  = (unsigned*)(w + 128 + (size_t)nbm * 96);
  float* histF  = (float*)(w + 128 + (size_t)nbm * 96 + (size_t)202 * nbh * 4);
  float* out = (float*)d_out;

  hipLaunchKernelGGL(k_main,    dim3(nbm), dim3(256),  0, stream, enc, dec, tru,
                     pmMse, pmCe, pmMn, pmMx, B, nbm);
  hipLaunchKernelGGL(k_reduce,  dim3(1),   dim3(1024), 0, stream, pmMse, pmCe, pmMn, pmMx, ws, nbm);
  hipLaunchKernelGGL(k_hist,    dim3(nbh), dim3(256),  0, stream, enc, lab, ws, ph, B, nbh);
  hipLaunchKernelGGL(k_hreduce, dim3(202), dim3(256),  0, stream, ph, histF, nbh);
  hipLaunchKernelGGL(k_final,   dim3(1),   dim3(64),   0, stream, histF, ws, out, B);
}

// Round 9
// 121.184 us; speedup vs baseline: 1.0490x; 1.0490x over previous
//
#include <hip/hip_runtime.h>
#include <math.h>

#define EPSF 1e-10f
#define TILE 32      // k_main rows per tile (fast path: B % TILE == 0)
#define TILEH 64     // k_hist rows per tile

struct WS { double sum_mse, sum_ce; float mn[10], mx[10]; };

typedef __attribute__((address_space(3))) unsigned int lds_u32_t;
typedef __attribute__((address_space(1))) const unsigned int glb_u32_t;
__device__ __forceinline__ void load_lds16(const void* g, void* l){
  __builtin_amdgcn_global_load_lds((glb_u32_t*)g, (lds_u32_t*)l, 16, 0, 0);
}

// CE over one softmax block, operands in LDS (compile-time offsets -> registers).
template<int S, int E>
__device__ __forceinline__ float ce_block_lds(const float* __restrict__ d,
                                              const float* __restrict__ t){
  constexpr int N = E - S;
  float dv[N];
  #pragma unroll
  for (int j = 0; j < N; j++) dv[j] = d[S + j];
  float mx = dv[0];
  #pragma unroll
  for (int j = 1; j < N; j++) mx = fmaxf(mx, dv[j]);
  float se = 0.f, dot = 0.f;
  #pragma unroll
  for (int j = 0; j < N; j++){ se += __expf(dv[j] - mx); dot += t[S + j] * dv[j]; }
  return mx + __logf(se) - dot;
}

// ---------------- k_main: reg-staged prefetch + 1-barrier double buffer ----------------
// tile = 880 float4 (dec 400, tru 400, enc 80). 256 threads:
//   rd0 = dp4[tid], rd1 = dp4[256+tid] (tid<144); same for tru; re = ep4[tid] (tid<80).
// Loop: ds_write(regs -> buf[k&1]) ; issue loads(k+1) ; __syncthreads ; compute(buf[k&1]).
// WAR safety: buf[k&1] last read by compute(k-2), which precedes barrier(k-1) in every
// wave's program order; write(k) happens after barrier(k-1). RAW: barrier(k) orders
// ds_write(k) before compute(k). Loads cannot sink below the barrier (memory clobber).
__global__ void k_main(const float* __restrict__ enc, const float* __restrict__ dec,
                       const float* __restrict__ tru,
                       double* __restrict__ pmMse, double* __restrict__ pmCe,
                       float* __restrict__ pmMn, float* __restrict__ pmMx,
                       int B, int nbm){
  __shared__ alignas(16) float bufD[2][TILE * 50];
  __shared__ alignas(16) float bufT[2][TILE * 50];
  __shared__ alignas(16) float bufE[2][TILE * 10];
  __shared__ double sMse[4], sCe[4];
  __shared__ float  sMn[4][10], sMx[4][10];

  const int tid  = threadIdx.x;
  const int wave = tid >> 6;
  const int lane = tid & 63;
  const int h    = tid >> 5;   // half-wave column group 0..7
  const int row  = tid & 31;

  float mn[10], mx[10];
  #pragma unroll
  for (int c = 0; c < 10; c++){ mn[c] = 3.4e38f; mx[c] = -3.4e38f; }
  float mse_acc = 0.f, ce_acc = 0.f;

  const int nTiles = B / TILE;
  int nT_loc = (blockIdx.x < nTiles) ? (nTiles - blockIdx.x + nbm - 1) / nbm : 0;

  float4 rd0, rd1, rt0, rt1, re;

  auto load_stage = [&](int k){
    const int tl = blockIdx.x + k * nbm;
    const float4* dp4 = reinterpret_cast<const float4*>(dec + (size_t)tl * (TILE * 50));
    const float4* tp4 = reinterpret_cast<const float4*>(tru + (size_t)tl * (TILE * 50));
    const float4* ep4 = reinterpret_cast<const float4*>(enc + (size_t)tl * (TILE * 10));
    rd0 = dp4[tid];
    rt0 = tp4[tid];
    if (tid < 144){ rd1 = dp4[256 + tid]; rt1 = tp4[256 + tid]; }
    if (tid < 80){ re = ep4[tid]; }
  };
  auto write_stage = [&](int b){
    float4* bD = reinterpret_cast<float4*>(bufD[b]);
    float4* bT = reinterpret_cast<float4*>(bufT[b]);
    float4* bE = reinterpret_cast<float4*>(bufE[b]);
    bD[tid] = rd0;
    bT[tid] = rt0;
    if (tid < 144){ bD[256 + tid] = rd1; bT[256 + tid] = rt1; }
    if (tid < 80){ bE[tid] = re; }
  };

  if (nT_loc > 0) load_stage(0);

  for (int k = 0; k < nT_loc; ++k){
    const int b = k & 1;
    write_stage(b);                    // compiler inserts vmcnt wait on regs
    if (k + 1 < nT_loc) load_stage(k + 1);   // issue next tile; lands under compute
    __syncthreads();                   // ds_writes visible; loads stay above (clobber)

    {
      const float* d = bufD[b] + row * 50;
      const float* t = bufT[b] + row * 50;
      const float* e = bufE[b] + row * 10;
      switch (h){
        case 0: {
          float m = 0.f;
          #pragma unroll
          for (int j = 0; j < 7; j++){ float df = d[j] - t[j]; m += df * df; }
          mse_acc += m;
          { float v = e[0]; mn[0] = fminf(mn[0], v); mx[0] = fmaxf(mx[0], v); }
          { float v = e[1]; mn[1] = fminf(mn[1], v); mx[1] = fmaxf(mx[1], v); }
        } break;
        case 1: {
          ce_acc += ce_block_lds< 7,19>(d, t);
          { float v = e[2]; mn[2] = fminf(mn[2], v); mx[2] = fmaxf(mx[2], v); }
        } break;
        case 2: {
          ce_acc += ce_block_lds<19,21>(d, t);
          ce_acc += ce_block_lds<21,25>(d, t);
          { float v = e[3]; mn[3] = fminf(mn[3], v); mx[3] = fmaxf(mx[3], v); }
        } break;
        case 3: {
          ce_acc += ce_block_lds<25,27>(d, t);
          ce_acc += ce_block_lds<27,29>(d, t);
          { float v = e[4]; mn[4] = fminf(mn[4], v); mx[4] = fmaxf(mx[4], v); }
        } break;
        case 4: {
          ce_acc += ce_block_lds<29,31>(d, t);
          ce_acc += ce_block_lds<31,34>(d, t);
          { float v = e[5]; mn[5] = fminf(mn[5], v); mx[5] = fmaxf(mx[5], v); }
          { float v = e[6]; mn[6] = fminf(mn[6], v); mx[6] = fmaxf(mx[6], v); }
        } break;
        case 5: {
          ce_acc += ce_block_lds<34,38>(d, t);
          { float v = e[7]; mn[7] = fminf(mn[7], v); mx[7] = fmaxf(mx[7], v); }
        } break;
        case 6: {
          ce_acc += ce_block_lds<38,50>(d, t);
          { float v = e[8]; mn[8] = fminf(mn[8], v); mx[8] = fmaxf(mx[8], v); }
        } break;
        default: {
          { float v = e[9]; mn[9] = fminf(mn[9], v); mx[9] = fmaxf(mx[9], v); }
        } break;
      }
    }
  }

  // ---- wave-level reduction ----
  #pragma unroll
  for (int c = 0; c < 10; c++){
    #pragma unroll
    for (int o = 32; o >= 1; o >>= 1){
      mn[c] = fminf(mn[c], __shfl_xor(mn[c], o));
      mx[c] = fmaxf(mx[c], __shfl_xor(mx[c], o));
    }
  }
  double mseD = (double)mse_acc, ceD = (double)ce_acc;
  #pragma unroll
  for (int o = 32; o >= 1; o >>= 1){
    mseD += __shfl_xor(mseD, o);
    ceD  += __shfl_xor(ceD,  o);
  }
  __syncthreads();   // all waves done with LDS buffers before reuse of sMse region? (separate arrays; barrier just orders epilogue)
  if (lane == 0){
    sMse[wave] = mseD; sCe[wave] = ceD;
    #pragma unroll
    for (int c = 0; c < 10; c++){ sMn[wave][c] = mn[c]; sMx[wave][c] = mx[c]; }
  }
  __syncthreads();
  if (tid == 0){
    pmMse[blockIdx.x] = sMse[0] + sMse[1] + sMse[2] + sMse[3];
    pmCe[blockIdx.x]  = sCe[0]  + sCe[1]  + sCe[2]  + sCe[3];
    #pragma unroll
    for (int c = 0; c < 10; c++){
      pmMn[c * nbm + blockIdx.x] = fminf(fminf(sMn[0][c], sMn[1][c]), fminf(sMn[2][c], sMn[3][c]));
      pmMx[c * nbm + blockIdx.x] = fmaxf(fmaxf(sMx[0][c], sMx[1][c]), fmaxf(sMx[2][c], sMx[3][c]));
    }
  }
}

// ---------------- fallback k_main (any B): per-row streaming ----------------
__global__ void k_main_fb(const float* __restrict__ enc, const float* __restrict__ dec,
                          const float* __restrict__ tru,
                          double* __restrict__ pmMse, double* __restrict__ pmCe,
                          float* __restrict__ pmMn, float* __restrict__ pmMx,
                          int B, int nbm){
  __shared__ double sMse[4], sCe[4];
  __shared__ float  sMn[4][10], sMx[4][10];
  const int tid = threadIdx.x, wave = tid >> 6, lane = tid & 63;
  float mn[10], mx[10];
  #pragma unroll
  for (int c = 0; c < 10; c++){ mn[c] = 3.4e38f; mx[c] = -3.4e38f; }
  float mse_acc = 0.f, ce_acc = 0.f;
  int stride = nbm * 256;
  for (int r = blockIdx.x * 256 + tid; r < B; r += stride){
    const float* e = enc + (size_t)r * 10;
    #pragma unroll
    for (int c = 0; c < 10; c++){ float v = e[c]; mn[c] = fminf(mn[c], v); mx[c] = fmaxf(mx[c], v); }
    const float* d = dec + (size_t)r * 50;
    const float* t = tru + (size_t)r * 50;
    float m = 0.f;
    #pragma unroll
    for (int j = 0; j < 7; j++){ float df = d[j] - t[j]; m += df * df; }
    mse_acc += m;
    ce_acc += ce_block_lds< 7,19>(d, t);
    ce_acc += ce_block_lds<19,21>(d, t);
    ce_acc += ce_block_lds<21,25>(d, t);
    ce_acc += ce_block_lds<25,27>(d, t);
    ce_acc += ce_block_lds<27,29>(d, t);
    ce_acc += ce_block_lds<29,31>(d, t);
    ce_acc += ce_block_lds<31,34>(d, t);
    ce_acc += ce_block_lds<34,38>(d, t);
    ce_acc += ce_block_lds<38,50>(d, t);
  }
  #pragma unroll
  for (int c = 0; c < 10; c++){
    #pragma unroll
    for (int o = 32; o >= 1; o >>= 1){
      mn[c] = fminf(mn[c], __shfl_xor(mn[c], o));
      mx[c] = fmaxf(mx[c], __shfl_xor(mx[c], o));
    }
  }
  double mseD = (double)mse_acc, ceD = (double)ce_acc;
  #pragma unroll
  for (int o = 32; o >= 1; o >>= 1){ mseD += __shfl_xor(mseD, o); ceD += __shfl_xor(ceD, o); }
  if (lane == 0){
    sMse[wave] = mseD; sCe[wave] = ceD;
    #pragma unroll
    for (int c = 0; c < 10; c++){ sMn[wave][c] = mn[c]; sMx[wave][c] = mx[c]; }
  }
  __syncthreads();
  if (tid == 0){
    pmMse[blockIdx.x] = sMse[0] + sMse[1] + sMse[2] + sMse[3];
    pmCe[blockIdx.x]  = sCe[0]  + sCe[1]  + sCe[2]  + sCe[3];
    #pragma unroll
    for (int c = 0; c < 10; c++){
      pmMn[c * nbm + blockIdx.x] = fminf(fminf(sMn[0][c], sMn[1][c]), fminf(sMn[2][c], sMn[3][c]));
      pmMx[c * nbm + blockIdx.x] = fmaxf(fmaxf(sMx[0][c], sMx[1][c]), fmaxf(sMx[2][c], sMx[3][c]));
    }
  }
}

__global__ void k_reduce(const double* __restrict__ pmMse, const double* __restrict__ pmCe,
                         const float* __restrict__ pmMn, const float* __restrict__ pmMx,
                         WS* __restrict__ ws, int nbm){
  __shared__ double sM[16], sC[16];
  __shared__ float  sMn[16][10], sMx[16][10];
  const int tid = threadIdx.x, wave = tid >> 6, lane = tid & 63;
  double ms = 0.0, ce = 0.0;
  float mn[10], mx[10];
  #pragma unroll
  for (int c = 0; c < 10; c++){ mn[c] = 3.4e38f; mx[c] = -3.4e38f; }
  for (int i = tid; i < nbm; i += 1024){
    ms += pmMse[i]; ce += pmCe[i];
    #pragma unroll
    for (int c = 0; c < 10; c++){
      mn[c] = fminf(mn[c], pmMn[c * nbm + i]);
      mx[c] = fmaxf(mx[c], pmMx[c * nbm + i]);
    }
  }
  #pragma unroll
  for (int o = 32; o >= 1; o >>= 1){
    ms += __shfl_xor(ms, o); ce += __shfl_xor(ce, o);
    #pragma unroll
    for (int c = 0; c < 10; c++){
      mn[c] = fminf(mn[c], __shfl_xor(mn[c], o));
      mx[c] = fmaxf(mx[c], __shfl_xor(mx[c], o));
    }
  }
  if (lane == 0){
    sM[wave] = ms; sC[wave] = ce;
    #pragma unroll
    for (int c = 0; c < 10; c++){ sMn[wave][c] = mn[c]; sMx[wave][c] = mx[c]; }
  }
  __syncthreads();
  if (tid == 0){
    double tm = 0.0, tc = 0.0;
    float rmn[10], rmx[10];
    #pragma unroll
    for (int c = 0; c < 10; c++){ rmn[c] = 3.4e38f; rmx[c] = -3.4e38f; }
    const int nw = (int)(blockDim.x >> 6);
    for (int w = 0; w < nw; w++){
      tm += sM[w]; tc += sC[w];
      #pragma unroll
      for (int c = 0; c < 10; c++){
        rmn[c] = fminf(rmn[c], sMn[w][c]);
        rmx[c] = fmaxf(rmx[c], sMx[w][c]);
      }
    }
    ws->sum_mse = tm; ws->sum_ce = tc;
    #pragma unroll
    for (int c = 0; c < 10; c++){ ws->mn[c] = rmn[c]; ws->mx[c] = rmx[c]; }
  }
}

// ---------------- k_hist: known-good dbuf gload_lds version (R6/R7) ----------------
__global__ void k_hist(const float* __restrict__ enc, const float* __restrict__ lab,
                       const WS* __restrict__ ws, unsigned* __restrict__ ph,
                       int B, int nbh){
  __shared__ unsigned int sh[202];
  __shared__ alignas(16) float bufE[2][TILEH * 10];
  __shared__ alignas(16) float bufL[2][TILEH * 3];

  const int tid  = threadIdx.x;
  const int wave = tid >> 6;
  const int lane = tid & 63;

  for (int i = tid; i < 202; i += 256) sh[i] = 0u;

  float mnv[10], wv[10];
  #pragma unroll
  for (int c = 0; c < 10; c++){
    float lo = ws->mn[c];
    float hi = ws->mx[c];
    mnv[c] = lo;
    wv[c]  = fmaxf(hi - lo, EPSF);
  }

  const int nTiles = (B + TILEH - 1) / TILEH;

  auto stage = [&](int b, int tl){
    const int rowsHere = min(TILEH, B - tl * TILEH);
    const size_t base10 = (size_t)tl * TILEH * 10;
    const size_t base3  = (size_t)tl * TILEH * 3;
    if (rowsHere == TILEH){
      const float4* ep4 = reinterpret_cast<const float4*>(enc + base10);
      const float4* lp4 = reinterpret_cast<const float4*>(lab + base3);
      float4* bE = reinterpret_cast<float4*>(bufE[b]);
      float4* bL = reinterpret_cast<float4*>(bufL[b]);
      { int i = tid; if (i < 160) load_lds16(ep4 + i, bE + i); }
      { int i = tid; if (i < 48)  load_lds16(lp4 + i, bL + i); }
    } else {
      const int ne = rowsHere * 10, nl = rowsHere * 3;
      for (int i = tid; i < ne; i += 256) bufE[b][i] = enc[base10 + i];
      for (int i = tid; i < nl; i += 256) bufL[b][i] = lab[base3 + i];
    }
  };

  const int t0 = blockIdx.x;
  if (t0 < nTiles) stage(0, t0);
  __syncthreads();

  int cur = 0;
  for (int tl = t0; tl < nTiles; tl += nbh){
    int nxt = tl + nbh;
    if (nxt < nTiles) stage(cur ^ 1, nxt);

    const int rowsHere = min(TILEH, B - tl * TILEH);
    const int rrow = lane;
    if (rrow < rowsHere){
      float g = bufL[cur][rrow * 3 + 1];
      int gi = (g == 0.0f) ? 0 : ((g == 1.0f) ? 1 : -1);
      if (gi >= 0){
        const float* e = bufE[cur] + rrow * 10;
        if (wave == 1) atomicAdd(&sh[200 + gi], 1u);
        #define DO_BIN(c) { \
          float bf = floorf((e[(c)] - mnv[(c)]) / wv[(c)] * 10.0f); \
          int b2 = (int)bf; b2 = b2 < 0 ? 0 : (b2 > 9 ? 9 : b2); \
          atomicAdd(&sh[gi * 100 + (c) * 10 + b2], 1u); }
        if (wave == 0){ DO_BIN(0) DO_BIN(1) DO_BIN(2) }
        else if (wave == 1){ DO_BIN(3) DO_BIN(4) }
        else if (wave == 2){ DO_BIN(5) DO_BIN(6) }
        else { DO_BIN(7) DO_BIN(8) DO_BIN(9) }
        #undef DO_BIN
      }
    }
    __syncthreads();
    cur ^= 1;
  }

  // transposed store: ph[entry * nbh + block]
  for (int i = tid; i < 202; i += 256) ph[(size_t)i * nbh + blockIdx.x] = sh[i];
}

// one block per histogram entry: coalesced sum over nbh partials, 4-way MLP
__global__ void k_hreduce(const unsigned* __restrict__ ph, float* __restrict__ histF, int nbh){
  __shared__ unsigned swv[4];
  const int e = blockIdx.x, tid = threadIdx.x, wave = tid >> 6, lane = tid & 63;
  const unsigned* p = ph + (size_t)e * nbh;
  unsigned s0 = 0, s1 = 0, s2 = 0, s3 = 0;
  int k = tid;
  for (; k + 768 < nbh; k += 1024){
    s0 += p[k]; s1 += p[k + 256]; s2 += p[k + 512]; s3 += p[k + 768];
  }
  for (; k < nbh; k += 256) s0 += p[k];
  unsigned s = s0 + s1 + s2 + s3;
  #pragma unroll
  for (int o = 32; o >= 1; o >>= 1) s += __shfl_xor(s, o);
  if (lane == 0) swv[wave] = s;
  __syncthreads();
  if (tid == 0) histF[e] = (float)(swv[0] + swv[1] + swv[2] + swv[3]);
}

__global__ void k_final(const float* __restrict__ histF, const WS* __restrict__ ws,
                        float* __restrict__ out, int B){
  const int tid = threadIdx.x;  // 64
  float dens = fmaxf(histF[200], 1.0f);
  float denm = fmaxf(histF[201], 1.0f);
  float kl = 0.f;
  for (int i = tid; i < 100; i += 64){
    float p = histF[i]       / dens;
    float q = histF[100 + i] / denm;
    if (p > 0.f) kl += p * logf(p / fmaxf(q, EPSF));
  }
  #pragma unroll
  for (int o = 32; o >= 1; o >>= 1) kl += __shfl_xor(kl, o);
  if (tid == 0){
    float mse = (float)(ws->sum_mse / (double)B);
    float ce  = (float)(ws->sum_ce  / (double)B);
    float akld = 0.5f * kl;
    out[0] = 0.5f * (mse + ce) + akld;
    out[1] = mse;
    out[2] = ce;
    out[3] = akld;
  }
}

extern "C" void kernel_launch(void* const* d_in, const int* in_sizes, int n_in,
                              void* d_out, int out_size, void* d_ws, size_t ws_size,
                              hipStream_t stream){
  const float* enc = (const float*)d_in[0];
  const float* dec = (const float*)d_in[1];
  const float* tru = (const float*)d_in[2];
  const float* lab = (const float*)d_in[3];
  int B = in_sizes[1] / 50;

  const bool fast = (B > 0) && (B % TILE == 0);

  int nbm = 1280;                      // 5 blocks/CU (28.4 KB LDS each)
  int nTm = fast ? (B / TILE) : ((B + 255) / 256);
  if (nbm > nTm && nTm > 0) nbm = nTm;
  if (nbm < 1) nbm = 1;

  int nbh = 2048;                      // 8 blocks/CU
  int nTh = (B + TILEH - 1) / TILEH;
  if (nbh > nTh && nTh > 0) nbh = nTh;
  if (nbh < 1) nbh = 1;

  // workspace: [WS 128][pmMse 8*nbm][pmCe 8*nbm][pmMn 40*nbm][pmMx 40*nbm][ph 202*nbh*4][histF 1024]
  while ((size_t)(128 + (size_t)nbm * 96 + (size_t)202 * nbh * 4 + 1024) > ws_size && nbm > 64){
    nbm >>= 1; nbh >>= 1;
  }
  char* w = (char*)d_ws;
  WS* ws = (WS*)w;
  double* pmMse = (double*)(w + 128);
  double* pmCe  = (double*)(w + 128 + (size_t)nbm * 8);
  float*  pmMn  = (float*)(w + 128 + (size_t)nbm * 16);
  float*  pmMx  = (float*)(w + 128 + (size_t)nbm * 16 + (size_t)nbm * 40);
  unsigned* ph  = (unsigned*)(w + 128 + (size_t)nbm * 96);
  float* histF  = (float*)(w + 128 + (size_t)nbm * 96 + (size_t)202 * nbh * 4);
  float* out = (float*)d_out;

  if (fast)
    hipLaunchKernelGGL(k_main,    dim3(nbm), dim3(256), 0, stream, enc, dec, tru,
                       pmMse, pmCe, pmMn, pmMx, B, nbm);
  else
    hipLaunchKernelGGL(k_main_fb, dim3(nbm), dim3(256), 0, stream, enc, dec, tru,
                       pmMse, pmCe, pmMn, pmMx, B, nbm);
  hipLaunchKernelGGL(k_reduce,  dim3(1),   dim3(1024), 0, stream, pmMse, pmCe, pmMn, pmMx, ws, nbm);
  hipLaunchKernelGGL(k_hist,    dim3(nbh), dim3(256),  0, stream, enc, lab, ws, ph, B, nbh);
  hipLaunchKernelGGL(k_hreduce, dim3(202), dim3(256),  0, stream, ph, histF, nbh);
  hipLaunchKernelGGL(k_final,   dim3(1),   dim3(64),   0, stream, histF, ws, out, B);
}